// Round 1
// 392.450 us; speedup vs baseline: 1.0061x; 1.0061x over previous
//
#include <hip/hip_runtime.h>
#include <math.h>

// MAPLoss: loss = mean_{b,m,n}[ 0.5*T^t Sy^{-1} T + 0.5*log(clip(det Sy, EPS)) ]
//          zeroed if max(t1) > 1e7.
// B=16, C=3, M=512, N=512. target/mu: [B,C,M,N]; sigma_y: [B,M,N,3,3].
// sigma_mu (d_in[2]) / sigma_n (d_in[3]) unused by the math.
//
// R4: counters showed latency-bound (HBM 17%, VALU 9%, VGPR=52): the compiler
//     serialized the 15 independent float4 loads to fit 52 VGPRs -> ~4 KB in
//     flight/CU -> 2.7 TB/s combined read ceiling (Little's law @ ~900 cy).
//     Fix: sigma staging via __builtin_amdgcn_global_load_lds width=16
//     (direct global->LDS DMA, no VGPR roundtrip, all 9 loads in flight).
//     LDS layout stays linear in lane order (wave-uniform base + lane*16).

#define EPS_F 1e-06f
#define T1_CLIP_F 1e7f

constexpr long long MN = 512LL * 512LL;           // 262144 = 2^18
constexpr long long P  = 16LL * MN;               // 4194304 pixels
constexpr int TPB  = 256;
constexpr int PPB  = 1024;                        // pixels per block (4/thread)
constexpr int NBLK = (int)(P / PPB);              // 4096
constexpr int SF4  = PPB * 9 / 4;                 // 2304 float4 of sigma per block

__device__ __forceinline__ void pixel_eval(
    float t0, float t1, float t2,
    float s00, float s01, float s02,
    float s10, float s11, float s12,
    float s20, float s21, float s22,
    float& t1v, float& dets)
{
    const float c00 = s11*s22 - s12*s21;
    const float c01 = s12*s20 - s10*s22;
    const float c02 = s10*s21 - s11*s20;
    const float det = s00*c00 + s01*c01 + s02*c02;

    const float a01 = s02*s21 - s01*s22;
    const float a02 = s01*s12 - s02*s11;
    const float a11 = s00*s22 - s02*s20;
    const float a12 = s02*s10 - s00*s12;
    const float a21 = s01*s20 - s00*s21;
    const float a22 = s00*s11 - s01*s10;

    const float q = t0*(c00*t0 + a01*t1 + a02*t2)
                  + t1*(c01*t0 + a11*t1 + a12*t2)
                  + t2*(c02*t0 + a21*t1 + a22*t2);

    t1v  = 0.5f * q / det;
    dets = 0.5f * logf(fmaxf(det, EPS_F));
}

__global__ __launch_bounds__(TPB) void map_partial(
    const float* __restrict__ target, const float* __restrict__ mu,
    const float* __restrict__ sigma, double* __restrict__ psum,
    float* __restrict__ pmax)
{
    __shared__ float4 sh[SF4];                    // 36 KB
    const int t = threadIdx.x;

    const long long blk_p0 = (long long)blockIdx.x * PPB;   // first pixel of block

    // ---- stage sigma: async global->LDS, width 16, no VGPR roundtrip ----
    // Per-lane global src; LDS dest = wave-uniform base + lane*16 (linear,
    // unpadded sh[k*TPB + t] matches exactly).
    const float4* sp = (const float4*)sigma + blk_p0 * 9 / 4;   // 2304 f4 / block
    #pragma unroll
    for (int k = 0; k < 9; ++k) {
        __builtin_amdgcn_global_load_lds(
            (const __attribute__((address_space(1))) void*)(sp + k * TPB + t),
            (__attribute__((address_space(3))) void*)(&sh[k * TPB + t]),
            16, 0, 0);
    }

    // ---- target/mu: coalesced float4 register loads, issued in the same
    //      window so they overlap the LDS staging ----
    const long long p0 = blk_p0 + 4LL * t;        // this thread's first pixel
    const long long b  = p0 >> 18;                // p0 / MN
    const long long r  = p0 & (MN - 1);
    const long long tb = b * (3 * MN) + r;

    const float4 tg0 = *(const float4*)(target + tb);
    const float4 tg1 = *(const float4*)(target + tb + MN);
    const float4 tg2 = *(const float4*)(target + tb + 2*MN);
    const float4 m0  = *(const float4*)(mu + tb);
    const float4 m1  = *(const float4*)(mu + tb + MN);
    const float4 m2  = *(const float4*)(mu + tb + 2*MN);

    __syncthreads();   // compiler emits s_waitcnt vmcnt(0) -> staging complete

    // ---- read back this thread's 4 pixels (36 floats = 9 float4) ----
    const float4* f = sh + 9 * t;
    const float4 f0 = f[0], f1 = f[1], f2 = f[2];
    const float4 f3 = f[3], f4_ = f[4], f5 = f[5];
    const float4 f6 = f[6], f7 = f[7], f8 = f[8];

    double acc = 0.0;
    float mx = 0.0f;   // t1 >= 0 (Sy is SPD)
    {
        float t1v, dets;
        // pixel 0: f0.xyzw f1.xyzw f2.x
        pixel_eval(tg0.x - m0.x, tg1.x - m1.x, tg2.x - m2.x,
                   f0.x, f0.y, f0.z, f0.w, f1.x, f1.y, f1.z, f1.w, f2.x,
                   t1v, dets);
        acc += (double)(t1v + dets); mx = fmaxf(mx, t1v);
        // pixel 1: f2.yzw f3.xyzw f4.xy
        pixel_eval(tg0.y - m0.y, tg1.y - m1.y, tg2.y - m2.y,
                   f2.y, f2.z, f2.w, f3.x, f3.y, f3.z, f3.w, f4_.x, f4_.y,
                   t1v, dets);
        acc += (double)(t1v + dets); mx = fmaxf(mx, t1v);
        // pixel 2: f4.zw f5.xyzw f6.xyz
        pixel_eval(tg0.z - m0.z, tg1.z - m1.z, tg2.z - m2.z,
                   f4_.z, f4_.w, f5.x, f5.y, f5.z, f5.w, f6.x, f6.y, f6.z,
                   t1v, dets);
        acc += (double)(t1v + dets); mx = fmaxf(mx, t1v);
        // pixel 3: f6.w f7.xyzw f8.xyzw
        pixel_eval(tg0.w - m0.w, tg1.w - m1.w, tg2.w - m2.w,
                   f6.w, f7.x, f7.y, f7.z, f7.w, f8.x, f8.y, f8.z, f8.w,
                   t1v, dets);
        acc += (double)(t1v + dets); mx = fmaxf(mx, t1v);
    }

    // ---- wave-64 shuffle reduce ----
    for (int off = 32; off > 0; off >>= 1) {
        acc += __shfl_down(acc, off, 64);
        mx = fmaxf(mx, __shfl_down(mx, off, 64));
    }
    __shared__ double ssum[TPB / 64];
    __shared__ float  smax[TPB / 64];
    const int lane = t & 63;
    const int wv   = t >> 6;
    if (lane == 0) { ssum[wv] = acc; smax[wv] = mx; }
    __syncthreads();
    if (t == 0) {
        double a = ssum[0] + ssum[1] + ssum[2] + ssum[3];
        float  m = fmaxf(fmaxf(smax[0], smax[1]), fmaxf(smax[2], smax[3]));
        psum[blockIdx.x] = a;
        pmax[blockIdx.x] = m;
    }
}

__global__ __launch_bounds__(TPB) void map_final(
    const double* __restrict__ psum, const float* __restrict__ pmax,
    float* __restrict__ out)
{
    double acc = 0.0;
    float mx = 0.0f;
    for (int i = threadIdx.x; i < NBLK; i += TPB) {
        acc += psum[i];
        mx = fmaxf(mx, pmax[i]);
    }
    for (int off = 32; off > 0; off >>= 1) {
        acc += __shfl_down(acc, off, 64);
        mx = fmaxf(mx, __shfl_down(mx, off, 64));
    }
    __shared__ double ssum[TPB / 64];
    __shared__ float  smax[TPB / 64];
    const int lane = threadIdx.x & 63;
    const int wv   = threadIdx.x >> 6;
    if (lane == 0) { ssum[wv] = acc; smax[wv] = mx; }
    __syncthreads();
    if (threadIdx.x == 0) {
        double a = ssum[0] + ssum[1] + ssum[2] + ssum[3];
        float  m = fmaxf(fmaxf(smax[0], smax[1]), fmaxf(smax[2], smax[3]));
        float loss = (float)(a / (double)P);
        out[0] = (m > T1_CLIP_F) ? 0.0f : loss;
    }
}

extern "C" void kernel_launch(void* const* d_in, const int* in_sizes, int n_in,
                              void* d_out, int out_size, void* d_ws, size_t ws_size,
                              hipStream_t stream) {
    const float* target  = (const float*)d_in[0];
    const float* mu      = (const float*)d_in[1];
    // d_in[2] = sigma_mu, d_in[3] = sigma_n : unused
    const float* sigma_y = (const float*)d_in[4];

    double* psum = (double*)d_ws;                                 // NBLK doubles
    float*  pmax = (float*)((char*)d_ws + NBLK * sizeof(double)); // NBLK floats

    map_partial<<<NBLK, TPB, 0, stream>>>(target, mu, sigma_y, psum, pmax);
    map_final<<<1, TPB, 0, stream>>>(psum, pmax, (float*)d_out);
}